// Round 4
// baseline (564.981 us; speedup 1.0000x reference)
//
#include <hip/hip_runtime.h>
#include <hip/hip_fp16.h>

#define NB 32
#define N 512
#define MAT (N*N)   // 262144

typedef _Float16 half8 __attribute__((ext_vector_type(8)));
typedef float f32x4 __attribute__((ext_vector_type(4)));

#define MSCALE 2048.0f
#define RMSCALE (1.0f/2048.0f)

// split x into fp16 h + fp16 m' where x ~= h + m' * 2^-11 (m' scaled to avoid denormals)
__device__ inline ushort2 split2(float x) {
    __half h = __float2half(x);
    __half m = __float2half((x - __half2float(h)) * MSCALE);
    return make_ushort2(__half_as_ushort(h), __half_as_ushort(m));
}

// async global->LDS DMA, 16B per lane; LDS dest = wave-uniform base + lane*16
__device__ inline void gload(const ushort* g, ushort* l) {
    __builtin_amdgcn_global_load_lds((const __attribute__((address_space(1))) void*)g,
                                     (__attribute__((address_space(3))) void*)l, 16, 0, 0);
}

__device__ inline float h2f(ushort u) {
    return __half2float(__builtin_bit_cast(__half, u));
}

// ---------------- luma + transpose: yT fp32 + yT fp16 planes ----------------
__global__ __launch_bounds__(256) void k_luma(const float* __restrict__ x, float* __restrict__ yT,
                                              ushort* __restrict__ Ph, ushort* __restrict__ Pm) {
    int b = blockIdx.y;
    int tile = blockIdx.x;
    int TR = (tile >> 3) * 64;
    int TC = (tile & 7) * 64;
    __shared__ float ld[64][65];
    int t = threadIdx.x;
    int r0 = t >> 4;
    int c4 = (t & 15) * 4;
    const float* xb = x + (size_t)b * 3 * MAT;
    #pragma unroll
    for (int q = 0; q < 4; ++q) {
        int row = r0 + q * 16;
        size_t off = (size_t)(TR + row) * N + TC + c4;
        float4 rr = *(const float4*)&xb[off];
        float4 gg = *(const float4*)&xb[off + MAT];
        float4 bb = *(const float4*)&xb[off + 2 * MAT];
        ld[row][c4 + 0] = 0.299f * rr.x + 0.587f * gg.x + 0.114f * bb.x;
        ld[row][c4 + 1] = 0.299f * rr.y + 0.587f * gg.y + 0.114f * bb.y;
        ld[row][c4 + 2] = 0.299f * rr.z + 0.587f * gg.z + 0.114f * bb.z;
        ld[row][c4 + 3] = 0.299f * rr.w + 0.587f * gg.w + 0.114f * bb.w;
    }
    __syncthreads();
    float* yTb = yT + (size_t)b * MAT;
    ushort* PhB = Ph + (size_t)b * MAT;
    ushort* PmB = Pm + (size_t)b * MAT;
    #pragma unroll
    for (int q = 0; q < 4; ++q) {
        int i = r0 + q * 16;
        float v0 = ld[c4 + 0][i];
        float v1 = ld[c4 + 1][i];
        float v2 = ld[c4 + 2][i];
        float v3 = ld[c4 + 3][i];
        size_t off = (size_t)(TC + i) * N + TR + c4;
        *(float4*)&yTb[off] = make_float4(v0, v1, v2, v3);
        ushort2 s0 = split2(v0), s1 = split2(v1), s2 = split2(v2), s3 = split2(v3);
        *(ushort4*)&PhB[off] = make_ushort4(s0.x, s1.x, s2.x, s3.x);
        *(ushort4*)&PmB[off] = make_ushort4(s0.y, s1.y, s2.y, s3.y);
    }
}

// ---------------- MFMA GEMM: C = alpha * P * P^T from fp16 planes ----------------
// C is symmetric: compute only the 10 upper-triangular 128x128 tile-blocks per batch
// (blockIdx.x = triangular index); off-diagonal blocks also store the transposed
// mirror tile, and count their Frobenius contribution twice.
// NPIN=2: hi+mid planes, 3 MFMA products. NPIN=1: h plane only, 1 product.
// Output planes: Qh always, Qm only if non-null.
template<int NPIN>
__global__ __launch_bounds__(256, 2) void k_gemm(const ushort* __restrict__ Ph, const ushort* __restrict__ Pm,
                                                 ushort* __restrict__ Qh, ushort* __restrict__ Qm,
                                                 const float* __restrict__ fsrc, float* __restrict__ fdst) {
    int b = blockIdx.z;
    const ushort* PhB = Ph + (size_t)b * MAT;
    const ushort* PmB = (NPIN == 2) ? Pm + (size_t)b * MAT : nullptr;

    __shared__ __align__(16) ushort sI[NPIN][128 * 32];
    __shared__ __align__(16) ushort sJ[NPIN][128 * 32];

    int t = threadIdx.x;
    // upper-triangle tile map for 4x4 blocks
    const int TBI[10] = {0, 0, 0, 0, 1, 1, 1, 2, 2, 3};
    const int TBJ[10] = {0, 1, 2, 3, 1, 2, 3, 2, 3, 3};
    int bx = blockIdx.x;
    int iBase = TBI[bx] * 128, jBase = TBJ[bx] * 128;
    bool diag = (iBase == jBase);

    int lane = t & 63, wv = t >> 6;
    int wi = wv >> 1, wj = wv & 1;
    int cc = lane & 15, cq = lane >> 4;
    int q8 = cq * 8;
    int lrow = lane >> 2;
    int lseg = lane & 3;

    float alpha = fsrc ? (1.0f / fsrc[b]) : 1.0f;

    f32x4 acc0[4][4], acc1[4][4];
    #pragma unroll
    for (int i = 0; i < 4; ++i)
        #pragma unroll
        for (int j = 0; j < 4; ++j) { acc0[i][j] = (f32x4)0.f; acc1[i][j] = (f32x4)0.f; }

    for (int k0 = 0; k0 < N; k0 += 32) {
        if (NPIN == 2) {
            if (diag) {
                #pragma unroll
                for (int j = 0; j < 4; ++j) {
                    int q = wv * 4 + j;
                    int pl = q >> 3, rg = q & 7;
                    const ushort* src = (pl ? PmB : PhB) + (size_t)(iBase + rg * 16 + lrow) * N + k0 + lseg * 8;
                    gload(src, &sI[pl][rg * 512]);
                }
            } else {
                #pragma unroll
                for (int j = 0; j < 8; ++j) {
                    int q = wv * 8 + j;
                    int panel = q >> 4, pl = (q >> 3) & 1, rg = q & 7;
                    int rb = panel ? jBase : iBase;
                    const ushort* src = (pl ? PmB : PhB) + (size_t)(rb + rg * 16 + lrow) * N + k0 + lseg * 8;
                    gload(src, panel ? &sJ[pl][rg * 512] : &sI[pl][rg * 512]);
                }
            }
        } else {
            if (diag) {
                #pragma unroll
                for (int j = 0; j < 2; ++j) {
                    int rg = wv * 2 + j;
                    const ushort* src = PhB + (size_t)(iBase + rg * 16 + lrow) * N + k0 + lseg * 8;
                    gload(src, &sI[0][rg * 512]);
                }
            } else {
                #pragma unroll
                for (int j = 0; j < 4; ++j) {
                    int q = wv * 4 + j;
                    int panel = q >> 3, rg = q & 7;
                    int rb = panel ? jBase : iBase;
                    const ushort* src = PhB + (size_t)(rb + rg * 16 + lrow) * N + k0 + lseg * 8;
                    gload(src, panel ? &sJ[0][rg * 512] : &sI[0][rg * 512]);
                }
            }
        }
        __syncthreads();

        const ushort(*Jb)[128 * 32] = diag ? sI : sJ;

        half8 bh[4], bm[4];
        #pragma unroll
        for (int ct = 0; ct < 4; ++ct) {
            int row = wj * 64 + ct * 16 + cc;
            bh[ct] = *(const half8*)&Jb[0][row * 32 + q8];
            if (NPIN == 2) bm[ct] = *(const half8*)&Jb[1][row * 32 + q8];
        }
        #pragma unroll
        for (int rt = 0; rt < 4; ++rt) {
            int row = wi * 64 + rt * 16 + cc;
            half8 ah = *(const half8*)&sI[0][row * 32 + q8];
            half8 am;
            if (NPIN == 2) am = *(const half8*)&sI[1][row * 32 + q8];
            #pragma unroll
            for (int ct = 0; ct < 4; ++ct) {
                acc0[rt][ct] = __builtin_amdgcn_mfma_f32_16x16x32_f16(ah, bh[ct], acc0[rt][ct], 0, 0, 0);
                if (NPIN == 2) {
                    acc1[rt][ct] = __builtin_amdgcn_mfma_f32_16x16x32_f16(ah, bm[ct], acc1[rt][ct], 0, 0, 0);
                    acc1[rt][ct] = __builtin_amdgcn_mfma_f32_16x16x32_f16(am, bh[ct], acc1[rt][ct], 0, 0, 0);
                }
            }
        }
        __syncthreads();
    }

    ushort* QhB = Qh + (size_t)b * MAT;
    ushort* QmB = Qm ? Qm + (size_t)b * MAT : nullptr;
    float ss = 0.f;
    #pragma unroll
    for (int rt = 0; rt < 4; ++rt) {
        int i0 = iBase + wi * 64 + rt * 16 + cq * 4;
        #pragma unroll
        for (int ct = 0; ct < 4; ++ct) {
            int j0 = jBase + wj * 64 + ct * 16 + cc;
            #pragma unroll
            for (int r = 0; r < 4; ++r) {
                float o = acc0[rt][ct][r];
                if (NPIN == 2) o += acc1[rt][ct][r] * RMSCALE;
                o *= alpha;
                ss += o * o;
                size_t idx = (size_t)(i0 + r) * N + j0;
                size_t idxT = (size_t)j0 * N + (i0 + r);   // mirror (transpose) position
                if (QmB) {
                    ushort2 hm = split2(o);
                    QhB[idx] = hm.x;
                    QmB[idx] = hm.y;
                    if (!diag) { QhB[idxT] = hm.x; QmB[idxT] = hm.y; }
                } else {
                    ushort hv = __half_as_ushort(__float2half(o));
                    QhB[idx] = hv;
                    if (!diag) QhB[idxT] = hv;
                }
            }
        }
    }

    if (fdst) {
        if (!diag) ss *= 2.f;                 // off-diag tiles appear twice in C
        for (int o = 32; o; o >>= 1) ss += __shfl_down(ss, o, 64);
        __shared__ float red[4];
        if (lane == 0) red[wv] = ss;
        __syncthreads();
        if (t == 0) atomicAdd(&fdst[b], red[0] + red[1] + red[2] + red[3]);
    }
}

// ---------------- distributed power iteration: one launch per matvec ----------------
// dst[b][j] = sum_c C[b][c][j] * src[b][c]   (C symmetric; column walk = coalesced).
// Grid (8, NB): 8 column-groups x 32 batches = 256 blocks, 512 threads.
// No per-iteration normalization: the GEMM chain's alpha scaling pins lambda1 ~ 1,
// so 8 unnormalized fp32 matvecs stay O(1); final norm applied in k_wfin.
// MODE 0: src = hash init (in-kernel). MODE 1: src = vin. MODE 2: src = vin and
// atomically accumulate ||dst||^2 into ssout[b].
template<int MODE>
__global__ __launch_bounds__(512) void k_piter(const ushort* __restrict__ Ch, const float* __restrict__ vin,
                                               float* __restrict__ dst, float* __restrict__ ssout) {
    int b = blockIdx.y, g = blockIdx.x;
    const ushort* C = Ch + (size_t)b * MAT;
    __shared__ float sv[N];
    __shared__ float part[32][65];
    int t = threadIdx.x;
    if (MODE == 0) {
        unsigned h = (unsigned)t * 1103515245u + 12345u;
        sv[t] = (float)((h >> 16) & 0x7fff) / 16384.f - 1.f;
    } else {
        sv[t] = vin[(size_t)b * N + t];
    }
    __syncthreads();

    int lane = t & 63, e = t >> 6;
    int j4 = (lane & 15) * 4;      // column offset within the 64-col group (quad)
    int cq = lane >> 4;            // row offset within a 4-row microstep
    int jb = g * 64;
    float a0 = 0.f, a1 = 0.f, a2 = 0.f, a3 = 0.f;
    #pragma unroll
    for (int c = 0; c < 64; c += 4) {
        int row = e * 64 + c + cq;
        ushort4 q = *(const ushort4*)&C[(size_t)row * N + jb + j4];
        float s = sv[row];
        a0 = fmaf(h2f(q.x), s, a0);
        a1 = fmaf(h2f(q.y), s, a1);
        a2 = fmaf(h2f(q.z), s, a2);
        a3 = fmaf(h2f(q.w), s, a3);
    }
    int pr = e * 4 + cq;
    part[pr][j4 + 0] = a0;
    part[pr][j4 + 1] = a1;
    part[pr][j4 + 2] = a2;
    part[pr][j4 + 3] = a3;
    __syncthreads();
    if (t < 64) {
        float o = 0.f;
        #pragma unroll
        for (int q = 0; q < 32; ++q) o += part[q][t];
        dst[(size_t)b * N + jb + t] = o;
        if (MODE == 2) {
            float val = o * o;
            #pragma unroll
            for (int s = 32; s; s >>= 1) val += __shfl_xor(val, s, 64);
            if (t == 0) atomicAdd(&ssout[b], val);
        }
    }
}

// ---------------- final: v_hat = v * rsqrt(ss); w = y * v_hat ----------------
// w[u] = sum_c yT[c][u] * v_hat[c].  Grid (8, NB), float4 column walk, same
// lane decomposition as k_piter.
__global__ __launch_bounds__(512) void k_wfin(const float* __restrict__ YT, const float* __restrict__ vin,
                                              const float* __restrict__ ss, float* __restrict__ vout,
                                              float* __restrict__ wout) {
    int b = blockIdx.y, g = blockIdx.x;
    const float* Yt = YT + (size_t)b * MAT;
    float rs = rsqrtf(ss[b]);
    __shared__ float sv[N];
    __shared__ float part[32][65];
    int t = threadIdx.x;
    sv[t] = vin[(size_t)b * N + t];        // unnormalized final iterate
    __syncthreads();

    int lane = t & 63, e = t >> 6;
    int j4 = (lane & 15) * 4;
    int cq = lane >> 4;
    int jb = g * 64;
    float a0 = 0.f, a1 = 0.f, a2 = 0.f, a3 = 0.f;
    #pragma unroll
    for (int c = 0; c < 64; c += 4) {
        int row = e * 64 + c + cq;
        float4 q = *(const float4*)&Yt[(size_t)row * N + jb + j4];
        float s = sv[row];
        a0 = fmaf(q.x, s, a0);
        a1 = fmaf(q.y, s, a1);
        a2 = fmaf(q.z, s, a2);
        a3 = fmaf(q.w, s, a3);
    }
    int pr = e * 4 + cq;
    part[pr][j4 + 0] = a0;
    part[pr][j4 + 1] = a1;
    part[pr][j4 + 2] = a2;
    part[pr][j4 + 3] = a3;
    __syncthreads();
    if (t < 64) {
        float w = 0.f;
        #pragma unroll
        for (int q = 0; q < 32; ++q) w += part[q][t];
        wout[(size_t)b * N + jb + t] = w * rs;
        vout[(size_t)b * N + jb + t] = sv[jb + t] * rs;
    }
}

// ---------------- out[b,i,j] = w[b,i] * v[b,j] ----------------
__global__ __launch_bounds__(256) void k_outer(const float* __restrict__ v, const float* __restrict__ w,
                                               float* __restrict__ out) {
    int tid = blockIdx.x * 256 + threadIdx.x;
    int b = tid >> 16;
    int rem = tid & 65535;
    int i = rem >> 7;
    int j4 = rem & 127;
    float wi = w[(size_t)b * N + i];
    float4 vv = ((const float4*)(v + (size_t)b * N))[j4];
    float4 o = {wi * vv.x, wi * vv.y, wi * vv.z, wi * vv.w};
    ((float4*)out)[tid] = o;
}

extern "C" void kernel_launch(void* const* d_in, const int* in_sizes, int n_in,
                              void* d_out, int out_size, void* d_ws, size_t ws_size,
                              hipStream_t stream) {
    const float* x = (const float*)d_in[0];
    float* out = (float*)d_out;
    char* base = (char*)d_ws;

    const size_t PL = (size_t)NB * MAT * sizeof(ushort);   // 16 MB per plane array
    ushort* AH = (ushort*)(base);
    ushort* AM = (ushort*)(base + PL);
    ushort* BH = (ushort*)(base + 2 * PL);
    ushort* BM = (ushort*)(base + 3 * PL);
    float*  fs = (float*)(base + 4 * PL);
    float*  vv = fs + 512;
    float*  ww = vv + (size_t)NB * N;
    float*  v2 = ww + (size_t)NB * N;
    float*  yT = out;                            // stage yT fp32 in d_out (read before k_outer overwrites)
    float*  ssf = fs + 256;                      // final ||v||^2 per batch (zeroed by memset below)

    hipMemsetAsync(fs, 0, 512 * sizeof(float), stream);
    k_luma<<<dim3(64, NB), 256, 0, stream>>>(x, yT, AH, AM);

    dim3 gg(10, 1, NB);   // 10 upper-triangular 128x128 tile-blocks per batch
    // P1..P3 dual-plane (sensitive small-gap stages), P3 emits h-only; P4..P9 single-plane.
    k_gemm<2><<<gg, 256, 0, stream>>>(AH, AM, BH, BM,      nullptr,   fs + 0*32); // B      = yT yT^T
    k_gemm<2><<<gg, 256, 0, stream>>>(BH, BM, AH, AM,      fs + 0*32, fs + 1*32); // B^2
    k_gemm<2><<<gg, 256, 0, stream>>>(AH, AM, BH, nullptr, fs + 1*32, fs + 2*32); // B^4   (h only)
    k_gemm<1><<<gg, 256, 0, stream>>>(BH, nullptr, AH, nullptr, fs + 2*32, fs + 3*32); // B^8
    k_gemm<1><<<gg, 256, 0, stream>>>(AH, nullptr, BH, nullptr, fs + 3*32, fs + 4*32); // B^16
    k_gemm<1><<<gg, 256, 0, stream>>>(BH, nullptr, AH, nullptr, fs + 4*32, fs + 5*32); // B^32
    k_gemm<1><<<gg, 256, 0, stream>>>(AH, nullptr, BH, nullptr, fs + 5*32, fs + 6*32); // B^64
    k_gemm<1><<<gg, 256, 0, stream>>>(BH, nullptr, AH, nullptr, fs + 6*32, fs + 7*32); // B^128
    k_gemm<1><<<gg, 256, 0, stream>>>(AH, nullptr, BH, nullptr, fs + 7*32, nullptr);   // B^256 (h) -> BH

    // 8 distributed power-iteration matvecs on C = B^256 (256 blocks each),
    // unnormalized; final norm^2 accumulated by the last one.
    dim3 gp(8, NB);
    k_piter<0><<<gp, 512, 0, stream>>>(BH, nullptr, vv, nullptr);   // hash -> vv
    k_piter<1><<<gp, 512, 0, stream>>>(BH, vv, v2, nullptr);
    k_piter<1><<<gp, 512, 0, stream>>>(BH, v2, vv, nullptr);
    k_piter<1><<<gp, 512, 0, stream>>>(BH, vv, v2, nullptr);
    k_piter<1><<<gp, 512, 0, stream>>>(BH, v2, vv, nullptr);
    k_piter<1><<<gp, 512, 0, stream>>>(BH, vv, v2, nullptr);
    k_piter<1><<<gp, 512, 0, stream>>>(BH, v2, vv, nullptr);
    k_piter<2><<<gp, 512, 0, stream>>>(BH, vv, v2, ssf);            // + ||v||^2 -> ssf

    k_wfin<<<gp, 512, 0, stream>>>(yT, v2, ssf, vv, ww);            // v_hat -> vv, w -> ww
    k_outer<<<8192, 256, 0, stream>>>(vv, ww, out);
}

// Round 5
// 456.343 us; speedup vs baseline: 1.2381x; 1.2381x over previous
//
#include <hip/hip_runtime.h>
#include <hip/hip_fp16.h>

#define NB 32
#define N 512
#define MAT (N*N)   // 262144

typedef _Float16 half8 __attribute__((ext_vector_type(8)));
typedef float f32x4 __attribute__((ext_vector_type(4)));

#define MSCALE 2048.0f
#define RMSCALE (1.0f/2048.0f)

// split x into fp16 h + fp16 m' where x ~= h + m' * 2^-11 (m' scaled to avoid denormals)
__device__ inline ushort2 split2(float x) {
    __half h = __float2half(x);
    __half m = __float2half((x - __half2float(h)) * MSCALE);
    return make_ushort2(__half_as_ushort(h), __half_as_ushort(m));
}

// async global->LDS DMA, 16B per lane; LDS dest = wave-uniform base + lane*16
__device__ inline void gload(const ushort* g, ushort* l) {
    __builtin_amdgcn_global_load_lds((const __attribute__((address_space(1))) void*)g,
                                     (__attribute__((address_space(3))) void*)l, 16, 0, 0);
}

__device__ inline float h2f(ushort u) {
    return __half2float(__builtin_bit_cast(__half, u));
}

// ---------------- luma + transpose: yT fp32 + yT fp16 planes ----------------
__global__ __launch_bounds__(256) void k_luma(const float* __restrict__ x, float* __restrict__ yT,
                                              ushort* __restrict__ Ph, ushort* __restrict__ Pm) {
    int b = blockIdx.y;
    int tile = blockIdx.x;
    int TR = (tile >> 3) * 64;
    int TC = (tile & 7) * 64;
    __shared__ float ld[64][65];
    int t = threadIdx.x;
    int r0 = t >> 4;
    int c4 = (t & 15) * 4;
    const float* xb = x + (size_t)b * 3 * MAT;
    #pragma unroll
    for (int q = 0; q < 4; ++q) {
        int row = r0 + q * 16;
        size_t off = (size_t)(TR + row) * N + TC + c4;
        float4 rr = *(const float4*)&xb[off];
        float4 gg = *(const float4*)&xb[off + MAT];
        float4 bb = *(const float4*)&xb[off + 2 * MAT];
        ld[row][c4 + 0] = 0.299f * rr.x + 0.587f * gg.x + 0.114f * bb.x;
        ld[row][c4 + 1] = 0.299f * rr.y + 0.587f * gg.y + 0.114f * bb.y;
        ld[row][c4 + 2] = 0.299f * rr.z + 0.587f * gg.z + 0.114f * bb.z;
        ld[row][c4 + 3] = 0.299f * rr.w + 0.587f * gg.w + 0.114f * bb.w;
    }
    __syncthreads();
    float* yTb = yT + (size_t)b * MAT;
    ushort* PhB = Ph + (size_t)b * MAT;
    ushort* PmB = Pm + (size_t)b * MAT;
    #pragma unroll
    for (int q = 0; q < 4; ++q) {
        int i = r0 + q * 16;
        float v0 = ld[c4 + 0][i];
        float v1 = ld[c4 + 1][i];
        float v2 = ld[c4 + 2][i];
        float v3 = ld[c4 + 3][i];
        size_t off = (size_t)(TC + i) * N + TR + c4;
        *(float4*)&yTb[off] = make_float4(v0, v1, v2, v3);
        ushort2 s0 = split2(v0), s1 = split2(v1), s2 = split2(v2), s3 = split2(v3);
        *(ushort4*)&PhB[off] = make_ushort4(s0.x, s1.x, s2.x, s3.x);
        *(ushort4*)&PmB[off] = make_ushort4(s0.y, s1.y, s2.y, s3.y);
    }
}

// ---------------- MFMA GEMM: C = alpha * P * P^T from fp16 planes ----------------
// Double-buffered K-loop (T3 minimum 2-phase): stage tile t+1 into buf^1 BEFORE
// computing tile t from buf; one __syncthreads() per K-step (its vmcnt(0)+lgkmcnt(0)
// drain guarantees both "next stage landed" and "all reads of buf done").
// NPIN=2: hi+mid planes, 3 MFMA products. NPIN=1: h plane only, 1 product.
template<int NPIN>
__global__ __launch_bounds__(256, 2) void k_gemm(const ushort* __restrict__ Ph, const ushort* __restrict__ Pm,
                                                 ushort* __restrict__ Qh, ushort* __restrict__ Qm,
                                                 const float* __restrict__ fsrc, float* __restrict__ fdst) {
    int b = blockIdx.z;
    const ushort* PhB = Ph + (size_t)b * MAT;
    const ushort* PmB = (NPIN == 2) ? Pm + (size_t)b * MAT : nullptr;

    __shared__ __align__(16) ushort sI[2][NPIN][128 * 32];
    __shared__ __align__(16) ushort sJ[2][NPIN][128 * 32];

    int t = threadIdx.x;
    int iBase = blockIdx.y * 128, jBase = blockIdx.x * 128;
    bool diag = (iBase == jBase);

    int lane = t & 63, wv = t >> 6;
    int wi = wv >> 1, wj = wv & 1;
    int cc = lane & 15, cq = lane >> 4;
    int q8 = cq * 8;
    int lrow = lane >> 2;
    int lseg = lane & 3;

    float alpha = fsrc ? (1.0f / fsrc[b]) : 1.0f;

    // stage one 32-wide K-tile into buffer `buf`
    auto stage = [&](int buf, int k0) {
        if (NPIN == 2) {
            if (diag) {
                #pragma unroll
                for (int j = 0; j < 4; ++j) {
                    int q = wv * 4 + j;
                    int pl = q >> 3, rg = q & 7;
                    const ushort* src = (pl ? PmB : PhB) + (size_t)(iBase + rg * 16 + lrow) * N + k0 + lseg * 8;
                    gload(src, &sI[buf][pl][rg * 512]);
                }
            } else {
                #pragma unroll
                for (int j = 0; j < 8; ++j) {
                    int q = wv * 8 + j;
                    int panel = q >> 4, pl = (q >> 3) & 1, rg = q & 7;
                    int rb = panel ? jBase : iBase;
                    const ushort* src = (pl ? PmB : PhB) + (size_t)(rb + rg * 16 + lrow) * N + k0 + lseg * 8;
                    gload(src, panel ? &sJ[buf][pl][rg * 512] : &sI[buf][pl][rg * 512]);
                }
            }
        } else {
            if (diag) {
                #pragma unroll
                for (int j = 0; j < 2; ++j) {
                    int rg = wv * 2 + j;
                    const ushort* src = PhB + (size_t)(iBase + rg * 16 + lrow) * N + k0 + lseg * 8;
                    gload(src, &sI[buf][0][rg * 512]);
                }
            } else {
                #pragma unroll
                for (int j = 0; j < 4; ++j) {
                    int q = wv * 4 + j;
                    int panel = q >> 3, rg = q & 7;
                    int rb = panel ? jBase : iBase;
                    const ushort* src = PhB + (size_t)(rb + rg * 16 + lrow) * N + k0 + lseg * 8;
                    gload(src, panel ? &sJ[buf][0][rg * 512] : &sI[buf][0][rg * 512]);
                }
            }
        }
    };

    f32x4 acc0[4][4], acc1[4][4];
    #pragma unroll
    for (int i = 0; i < 4; ++i)
        #pragma unroll
        for (int j = 0; j < 4; ++j) { acc0[i][j] = (f32x4)0.f; acc1[i][j] = (f32x4)0.f; }

    stage(0, 0);
    __syncthreads();                       // drain prologue stage

    for (int k0 = 0; k0 < N; k0 += 32) {
        int cur = (k0 >> 5) & 1;
        if (k0 + 32 < N) stage(cur ^ 1, k0 + 32);   // prefetch next K-tile (in flight during compute)

        const ushort(*Ib)[128 * 32] = sI[cur];
        const ushort(*Jb)[128 * 32] = diag ? sI[cur] : sJ[cur];

        half8 bh[4], bm[4];
        #pragma unroll
        for (int ct = 0; ct < 4; ++ct) {
            int row = wj * 64 + ct * 16 + cc;
            bh[ct] = *(const half8*)&Jb[0][row * 32 + q8];
            if (NPIN == 2) bm[ct] = *(const half8*)&Jb[1][row * 32 + q8];
        }
        #pragma unroll
        for (int rt = 0; rt < 4; ++rt) {
            int row = wi * 64 + rt * 16 + cc;
            half8 ah = *(const half8*)&Ib[0][row * 32 + q8];
            half8 am;
            if (NPIN == 2) am = *(const half8*)&Ib[1][row * 32 + q8];
            #pragma unroll
            for (int ct = 0; ct < 4; ++ct) {
                acc0[rt][ct] = __builtin_amdgcn_mfma_f32_16x16x32_f16(ah, bh[ct], acc0[rt][ct], 0, 0, 0);
                if (NPIN == 2) {
                    acc1[rt][ct] = __builtin_amdgcn_mfma_f32_16x16x32_f16(ah, bm[ct], acc1[rt][ct], 0, 0, 0);
                    acc1[rt][ct] = __builtin_amdgcn_mfma_f32_16x16x32_f16(am, bh[ct], acc1[rt][ct], 0, 0, 0);
                }
            }
        }
        __syncthreads();                   // one barrier per K-step: next buf ready + reads of cur done
    }

    ushort* QhB = Qh + (size_t)b * MAT;
    ushort* QmB = Qm ? Qm + (size_t)b * MAT : nullptr;
    float ss = 0.f;
    #pragma unroll
    for (int rt = 0; rt < 4; ++rt) {
        int i0 = iBase + wi * 64 + rt * 16 + cq * 4;
        #pragma unroll
        for (int ct = 0; ct < 4; ++ct) {
            int j0 = jBase + wj * 64 + ct * 16 + cc;
            #pragma unroll
            for (int r = 0; r < 4; ++r) {
                float o = acc0[rt][ct][r];
                if (NPIN == 2) o += acc1[rt][ct][r] * RMSCALE;
                o *= alpha;
                ss += o * o;
                size_t idx = (size_t)(i0 + r) * N + j0;
                if (QmB) {
                    ushort2 hm = split2(o);
                    QhB[idx] = hm.x;
                    QmB[idx] = hm.y;
                } else {
                    QhB[idx] = __half_as_ushort(__float2half(o));
                }
            }
        }
    }

    if (fdst) {
        for (int o = 32; o; o >>= 1) ss += __shfl_down(ss, o, 64);
        __shared__ float red[4];
        if (lane == 0) red[wv] = ss;
        __syncthreads();
        if (t == 0) atomicAdd(&fdst[b], red[0] + red[1] + red[2] + red[3]);
    }
}

// ---------------- distributed power iteration: one launch per matvec ----------------
// dst[b][j] = sum_c C[b][c][j] * src[b][c]   (C symmetric; column walk = coalesced).
// Grid (8, NB): 8 column-groups x 32 batches = 256 blocks, 512 threads.
// No per-iteration normalization: the GEMM chain's alpha scaling pins lambda1 ~ 1,
// so 8 unnormalized fp32 matvecs stay O(1); final norm applied in k_wfin.
// MODE 0: src = hash init (in-kernel). MODE 1: src = vin. MODE 2: src = vin and
// atomically accumulate ||dst||^2 into ssout[b].
template<int MODE>
__global__ __launch_bounds__(512) void k_piter(const ushort* __restrict__ Ch, const float* __restrict__ vin,
                                               float* __restrict__ dst, float* __restrict__ ssout) {
    int b = blockIdx.y, g = blockIdx.x;
    const ushort* C = Ch + (size_t)b * MAT;
    __shared__ float sv[N];
    __shared__ float part[32][65];
    int t = threadIdx.x;
    if (MODE == 0) {
        unsigned h = (unsigned)t * 1103515245u + 12345u;
        sv[t] = (float)((h >> 16) & 0x7fff) / 16384.f - 1.f;
    } else {
        sv[t] = vin[(size_t)b * N + t];
    }
    __syncthreads();

    int lane = t & 63, e = t >> 6;
    int j4 = (lane & 15) * 4;      // column offset within the 64-col group (quad)
    int cq = lane >> 4;            // row offset within a 4-row microstep
    int jb = g * 64;
    float a0 = 0.f, a1 = 0.f, a2 = 0.f, a3 = 0.f;
    #pragma unroll
    for (int c = 0; c < 64; c += 4) {
        int row = e * 64 + c + cq;
        ushort4 q = *(const ushort4*)&C[(size_t)row * N + jb + j4];
        float s = sv[row];
        a0 = fmaf(h2f(q.x), s, a0);
        a1 = fmaf(h2f(q.y), s, a1);
        a2 = fmaf(h2f(q.z), s, a2);
        a3 = fmaf(h2f(q.w), s, a3);
    }
    int pr = e * 4 + cq;
    part[pr][j4 + 0] = a0;
    part[pr][j4 + 1] = a1;
    part[pr][j4 + 2] = a2;
    part[pr][j4 + 3] = a3;
    __syncthreads();
    if (t < 64) {
        float o = 0.f;
        #pragma unroll
        for (int q = 0; q < 32; ++q) o += part[q][t];
        dst[(size_t)b * N + jb + t] = o;
        if (MODE == 2) {
            float val = o * o;
            #pragma unroll
            for (int s = 32; s; s >>= 1) val += __shfl_xor(val, s, 64);
            if (t == 0) atomicAdd(&ssout[b], val);
        }
    }
}

// ---------------- final: v_hat = v * rsqrt(ss); w = y * v_hat ----------------
// w[u] = sum_c yT[c][u] * v_hat[c].  Grid (8, NB), float4 column walk, same
// lane decomposition as k_piter.
__global__ __launch_bounds__(512) void k_wfin(const float* __restrict__ YT, const float* __restrict__ vin,
                                              const float* __restrict__ ss, float* __restrict__ vout,
                                              float* __restrict__ wout) {
    int b = blockIdx.y, g = blockIdx.x;
    const float* Yt = YT + (size_t)b * MAT;
    float rs = rsqrtf(ss[b]);
    __shared__ float sv[N];
    __shared__ float part[32][65];
    int t = threadIdx.x;
    sv[t] = vin[(size_t)b * N + t];        // unnormalized final iterate
    __syncthreads();

    int lane = t & 63, e = t >> 6;
    int j4 = (lane & 15) * 4;
    int cq = lane >> 4;
    int jb = g * 64;
    float a0 = 0.f, a1 = 0.f, a2 = 0.f, a3 = 0.f;
    #pragma unroll
    for (int c = 0; c < 64; c += 4) {
        int row = e * 64 + c + cq;
        float4 q = *(const float4*)&Yt[(size_t)row * N + jb + j4];
        float s = sv[row];
        a0 = fmaf(q.x, s, a0);
        a1 = fmaf(q.y, s, a1);
        a2 = fmaf(q.z, s, a2);
        a3 = fmaf(q.w, s, a3);
    }
    int pr = e * 4 + cq;
    part[pr][j4 + 0] = a0;
    part[pr][j4 + 1] = a1;
    part[pr][j4 + 2] = a2;
    part[pr][j4 + 3] = a3;
    __syncthreads();
    if (t < 64) {
        float w = 0.f;
        #pragma unroll
        for (int q = 0; q < 32; ++q) w += part[q][t];
        wout[(size_t)b * N + jb + t] = w * rs;
        vout[(size_t)b * N + jb + t] = sv[jb + t] * rs;
    }
}

// ---------------- out[b,i,j] = w[b,i] * v[b,j] ----------------
__global__ __launch_bounds__(256) void k_outer(const float* __restrict__ v, const float* __restrict__ w,
                                               float* __restrict__ out) {
    int tid = blockIdx.x * 256 + threadIdx.x;
    int b = tid >> 16;
    int rem = tid & 65535;
    int i = rem >> 7;
    int j4 = rem & 127;
    float wi = w[(size_t)b * N + i];
    float4 vv = ((const float4*)(v + (size_t)b * N))[j4];
    float4 o = {wi * vv.x, wi * vv.y, wi * vv.z, wi * vv.w};
    ((float4*)out)[tid] = o;
}

extern "C" void kernel_launch(void* const* d_in, const int* in_sizes, int n_in,
                              void* d_out, int out_size, void* d_ws, size_t ws_size,
                              hipStream_t stream) {
    const float* x = (const float*)d_in[0];
    float* out = (float*)d_out;
    char* base = (char*)d_ws;

    const size_t PL = (size_t)NB * MAT * sizeof(ushort);   // 16 MB per plane array
    ushort* AH = (ushort*)(base);
    ushort* AM = (ushort*)(base + PL);
    ushort* BH = (ushort*)(base + 2 * PL);
    ushort* BM = (ushort*)(base + 3 * PL);
    float*  fs = (float*)(base + 4 * PL);
    float*  vv = fs + 512;
    float*  ww = vv + (size_t)NB * N;
    float*  v2 = ww + (size_t)NB * N;
    float*  yT = out;                            // stage yT fp32 in d_out (read before k_outer overwrites)
    float*  ssf = fs + 256;                      // final ||v||^2 per batch (zeroed by memset below)

    hipMemsetAsync(fs, 0, 512 * sizeof(float), stream);
    k_luma<<<dim3(64, NB), 256, 0, stream>>>(x, yT, AH, AM);

    dim3 gg(4, 4, NB);
    // P1..P3 dual-plane (sensitive small-gap stages), P3 emits h-only; P4..P9 single-plane.
    k_gemm<2><<<gg, 256, 0, stream>>>(AH, AM, BH, BM,      nullptr,   fs + 0*32); // B      = yT yT^T
    k_gemm<2><<<gg, 256, 0, stream>>>(BH, BM, AH, AM,      fs + 0*32, fs + 1*32); // B^2
    k_gemm<2><<<gg, 256, 0, stream>>>(AH, AM, BH, nullptr, fs + 1*32, fs + 2*32); // B^4   (h only)
    k_gemm<1><<<gg, 256, 0, stream>>>(BH, nullptr, AH, nullptr, fs + 2*32, fs + 3*32); // B^8
    k_gemm<1><<<gg, 256, 0, stream>>>(AH, nullptr, BH, nullptr, fs + 3*32, fs + 4*32); // B^16
    k_gemm<1><<<gg, 256, 0, stream>>>(BH, nullptr, AH, nullptr, fs + 4*32, fs + 5*32); // B^32
    k_gemm<1><<<gg, 256, 0, stream>>>(AH, nullptr, BH, nullptr, fs + 5*32, fs + 6*32); // B^64
    k_gemm<1><<<gg, 256, 0, stream>>>(BH, nullptr, AH, nullptr, fs + 6*32, fs + 7*32); // B^128
    k_gemm<1><<<gg, 256, 0, stream>>>(AH, nullptr, BH, nullptr, fs + 7*32, nullptr);   // B^256 (h) -> BH

    // 8 distributed power-iteration matvecs on C = B^256 (256 blocks each),
    // unnormalized; final norm^2 accumulated by the last one.
    dim3 gp(8, NB);
    k_piter<0><<<gp, 512, 0, stream>>>(BH, nullptr, vv, nullptr);   // hash -> vv
    k_piter<1><<<gp, 512, 0, stream>>>(BH, vv, v2, nullptr);
    k_piter<1><<<gp, 512, 0, stream>>>(BH, v2, vv, nullptr);
    k_piter<1><<<gp, 512, 0, stream>>>(BH, vv, v2, nullptr);
    k_piter<1><<<gp, 512, 0, stream>>>(BH, v2, vv, nullptr);
    k_piter<1><<<gp, 512, 0, stream>>>(BH, vv, v2, nullptr);
    k_piter<1><<<gp, 512, 0, stream>>>(BH, v2, vv, nullptr);
    k_piter<2><<<gp, 512, 0, stream>>>(BH, vv, v2, ssf);            // + ||v||^2 -> ssf

    k_wfin<<<gp, 512, 0, stream>>>(yT, v2, ssf, vv, ww);            // v_hat -> vv, w -> ww
    k_outer<<<8192, 256, 0, stream>>>(vv, ww, out);
}

// Round 6
// 406.804 us; speedup vs baseline: 1.3888x; 1.1218x over previous
//
#include <hip/hip_runtime.h>
#include <hip/hip_fp16.h>

#define NB 32
#define N 512
#define MAT (N*N)   // 262144

typedef _Float16 half8 __attribute__((ext_vector_type(8)));
typedef float f32x4 __attribute__((ext_vector_type(4)));

#define MSCALE 2048.0f
#define RMSCALE (1.0f/2048.0f)

// split x into fp16 h + fp16 m' where x ~= h + m' * 2^-11 (m' scaled to avoid denormals)
__device__ inline ushort2 split2(float x) {
    __half h = __float2half(x);
    __half m = __float2half((x - __half2float(h)) * MSCALE);
    return make_ushort2(__half_as_ushort(h), __half_as_ushort(m));
}

// async global->LDS DMA, 16B per lane; LDS dest = wave-uniform base + lane*16
__device__ inline void gload(const ushort* g, ushort* l) {
    __builtin_amdgcn_global_load_lds((const __attribute__((address_space(1))) void*)g,
                                     (__attribute__((address_space(3))) void*)l, 16, 0, 0);
}

__device__ inline float h2f(ushort u) {
    return __half2float(__builtin_bit_cast(__half, u));
}

// ---------------- luma + transpose: yT fp32 + yT fp16 planes ----------------
__global__ __launch_bounds__(256) void k_luma(const float* __restrict__ x, float* __restrict__ yT,
                                              ushort* __restrict__ Ph, ushort* __restrict__ Pm) {
    int b = blockIdx.y;
    int tile = blockIdx.x;
    int TR = (tile >> 3) * 64;
    int TC = (tile & 7) * 64;
    __shared__ float ld[64][65];
    int t = threadIdx.x;
    int r0 = t >> 4;
    int c4 = (t & 15) * 4;
    const float* xb = x + (size_t)b * 3 * MAT;
    #pragma unroll
    for (int q = 0; q < 4; ++q) {
        int row = r0 + q * 16;
        size_t off = (size_t)(TR + row) * N + TC + c4;
        float4 rr = *(const float4*)&xb[off];
        float4 gg = *(const float4*)&xb[off + MAT];
        float4 bb = *(const float4*)&xb[off + 2 * MAT];
        ld[row][c4 + 0] = 0.299f * rr.x + 0.587f * gg.x + 0.114f * bb.x;
        ld[row][c4 + 1] = 0.299f * rr.y + 0.587f * gg.y + 0.114f * bb.y;
        ld[row][c4 + 2] = 0.299f * rr.z + 0.587f * gg.z + 0.114f * bb.z;
        ld[row][c4 + 3] = 0.299f * rr.w + 0.587f * gg.w + 0.114f * bb.w;
    }
    __syncthreads();
    float* yTb = yT + (size_t)b * MAT;
    ushort* PhB = Ph + (size_t)b * MAT;
    ushort* PmB = Pm + (size_t)b * MAT;
    #pragma unroll
    for (int q = 0; q < 4; ++q) {
        int i = r0 + q * 16;
        float v0 = ld[c4 + 0][i];
        float v1 = ld[c4 + 1][i];
        float v2 = ld[c4 + 2][i];
        float v3 = ld[c4 + 3][i];
        size_t off = (size_t)(TC + i) * N + TR + c4;
        *(float4*)&yTb[off] = make_float4(v0, v1, v2, v3);
        ushort2 s0 = split2(v0), s1 = split2(v1), s2 = split2(v2), s3 = split2(v3);
        *(ushort4*)&PhB[off] = make_ushort4(s0.x, s1.x, s2.x, s3.x);
        *(ushort4*)&PmB[off] = make_ushort4(s0.y, s1.y, s2.y, s3.y);
    }
}

// ---------------- MFMA GEMM: C = alpha * P * P^T from fp16 planes ----------------
// Double-buffered K-loop; 1D grid of 512 blocks with batch-clustered XCD decode:
// xcd = bid & 7 (presumed dispatch round-robin), XCD x owns batches {x, x+8, x+16,
// x+24} -> all 16 tile-blocks of a batch share one L2 (panel fetched once per XCD,
// L2-hit latency instead of L3/HBM).
// NPIN=2: hi+mid planes, 3 MFMA products. NPIN=1: h plane only, 1 product.
template<int NPIN>
__global__ __launch_bounds__(256, 2) void k_gemm(const ushort* __restrict__ Ph, const ushort* __restrict__ Pm,
                                                 ushort* __restrict__ Qh, ushort* __restrict__ Qm,
                                                 const float* __restrict__ fsrc, float* __restrict__ fdst) {
    int bid = blockIdx.x;
    int xcd = bid & 7, q0 = bid >> 3;
    int b = xcd + 8 * (q0 >> 4);          // batch: 4 per XCD
    int tile = q0 & 15;                    // 16 tiles of this batch on the same XCD
    const ushort* PhB = Ph + (size_t)b * MAT;
    const ushort* PmB = (NPIN == 2) ? Pm + (size_t)b * MAT : nullptr;

    __shared__ __align__(16) ushort sI[2][NPIN][128 * 32];
    __shared__ __align__(16) ushort sJ[2][NPIN][128 * 32];

    int t = threadIdx.x;
    int iBase = (tile >> 2) * 128, jBase = (tile & 3) * 128;
    bool diag = (iBase == jBase);

    int lane = t & 63, wv = t >> 6;
    int wi = wv >> 1, wj = wv & 1;
    int cc = lane & 15, cq = lane >> 4;
    int q8 = cq * 8;
    int lrow = lane >> 2;
    int lseg = lane & 3;

    float alpha = fsrc ? (1.0f / fsrc[b]) : 1.0f;

    // stage one 32-wide K-tile into buffer `buf`
    auto stage = [&](int buf, int k0) {
        if (NPIN == 2) {
            if (diag) {
                #pragma unroll
                for (int j = 0; j < 4; ++j) {
                    int q = wv * 4 + j;
                    int pl = q >> 3, rg = q & 7;
                    const ushort* src = (pl ? PmB : PhB) + (size_t)(iBase + rg * 16 + lrow) * N + k0 + lseg * 8;
                    gload(src, &sI[buf][pl][rg * 512]);
                }
            } else {
                #pragma unroll
                for (int j = 0; j < 8; ++j) {
                    int q = wv * 8 + j;
                    int panel = q >> 4, pl = (q >> 3) & 1, rg = q & 7;
                    int rb = panel ? jBase : iBase;
                    const ushort* src = (pl ? PmB : PhB) + (size_t)(rb + rg * 16 + lrow) * N + k0 + lseg * 8;
                    gload(src, panel ? &sJ[buf][pl][rg * 512] : &sI[buf][pl][rg * 512]);
                }
            }
        } else {
            if (diag) {
                #pragma unroll
                for (int j = 0; j < 2; ++j) {
                    int rg = wv * 2 + j;
                    const ushort* src = PhB + (size_t)(iBase + rg * 16 + lrow) * N + k0 + lseg * 8;
                    gload(src, &sI[buf][0][rg * 512]);
                }
            } else {
                #pragma unroll
                for (int j = 0; j < 4; ++j) {
                    int q = wv * 4 + j;
                    int panel = q >> 3, rg = q & 7;
                    int rb = panel ? jBase : iBase;
                    const ushort* src = PhB + (size_t)(rb + rg * 16 + lrow) * N + k0 + lseg * 8;
                    gload(src, panel ? &sJ[buf][0][rg * 512] : &sI[buf][0][rg * 512]);
                }
            }
        }
    };

    f32x4 acc0[4][4], acc1[4][4];
    #pragma unroll
    for (int i = 0; i < 4; ++i)
        #pragma unroll
        for (int j = 0; j < 4; ++j) { acc0[i][j] = (f32x4)0.f; acc1[i][j] = (f32x4)0.f; }

    stage(0, 0);
    __syncthreads();                       // drain prologue stage

    for (int k0 = 0; k0 < N; k0 += 32) {
        int cur = (k0 >> 5) & 1;
        if (k0 + 32 < N) stage(cur ^ 1, k0 + 32);   // prefetch next K-tile (in flight during compute)

        const ushort(*Ib)[128 * 32] = sI[cur];
        const ushort(*Jb)[128 * 32] = diag ? sI[cur] : sJ[cur];

        half8 bh[4], bm[4];
        #pragma unroll
        for (int ct = 0; ct < 4; ++ct) {
            int row = wj * 64 + ct * 16 + cc;
            bh[ct] = *(const half8*)&Jb[0][row * 32 + q8];
            if (NPIN == 2) bm[ct] = *(const half8*)&Jb[1][row * 32 + q8];
        }
        #pragma unroll
        for (int rt = 0; rt < 4; ++rt) {
            int row = wi * 64 + rt * 16 + cc;
            half8 ah = *(const half8*)&Ib[0][row * 32 + q8];
            half8 am;
            if (NPIN == 2) am = *(const half8*)&Ib[1][row * 32 + q8];
            #pragma unroll
            for (int ct = 0; ct < 4; ++ct) {
                acc0[rt][ct] = __builtin_amdgcn_mfma_f32_16x16x32_f16(ah, bh[ct], acc0[rt][ct], 0, 0, 0);
                if (NPIN == 2) {
                    acc1[rt][ct] = __builtin_amdgcn_mfma_f32_16x16x32_f16(ah, bm[ct], acc1[rt][ct], 0, 0, 0);
                    acc1[rt][ct] = __builtin_amdgcn_mfma_f32_16x16x32_f16(am, bh[ct], acc1[rt][ct], 0, 0, 0);
                }
            }
        }
        __syncthreads();                   // one barrier per K-step: next buf ready + reads of cur done
    }

    ushort* QhB = Qh + (size_t)b * MAT;
    ushort* QmB = Qm ? Qm + (size_t)b * MAT : nullptr;
    float ss = 0.f;
    #pragma unroll
    for (int rt = 0; rt < 4; ++rt) {
        int i0 = iBase + wi * 64 + rt * 16 + cq * 4;
        #pragma unroll
        for (int ct = 0; ct < 4; ++ct) {
            int j0 = jBase + wj * 64 + ct * 16 + cc;
            #pragma unroll
            for (int r = 0; r < 4; ++r) {
                float o = acc0[rt][ct][r];
                if (NPIN == 2) o += acc1[rt][ct][r] * RMSCALE;
                o *= alpha;
                ss += o * o;
                size_t idx = (size_t)(i0 + r) * N + j0;
                if (QmB) {
                    ushort2 hm = split2(o);
                    QhB[idx] = hm.x;
                    QmB[idx] = hm.y;
                } else {
                    QhB[idx] = __half_as_ushort(__float2half(o));
                }
            }
        }
    }

    if (fdst) {
        for (int o = 32; o; o >>= 1) ss += __shfl_down(ss, o, 64);
        __shared__ float red[4];
        if (lane == 0) red[wv] = ss;
        __syncthreads();
        if (t == 0) atomicAdd(&fdst[b], red[0] + red[1] + red[2] + red[3]);
    }
}

// ---------------- distributed power iteration: one launch per matvec ----------------
// dst[b][j] = sum_c C[b][c][j] * src[b][c]   (C symmetric; column walk = coalesced).
// Grid (8, NB): 8 column-groups x 32 batches = 256 blocks, 512 threads.
// No per-iteration normalization: the GEMM chain's alpha scaling pins lambda1 ~ 1,
// so 8 unnormalized fp32 matvecs stay O(1); final norm applied in k_wfin.
// MODE 0: src = hash init (in-kernel). MODE 1: src = vin. MODE 2: src = vin and
// atomically accumulate ||dst||^2 into ssout[b].
template<int MODE>
__global__ __launch_bounds__(512) void k_piter(const ushort* __restrict__ Ch, const float* __restrict__ vin,
                                               float* __restrict__ dst, float* __restrict__ ssout) {
    int b = blockIdx.y, g = blockIdx.x;
    const ushort* C = Ch + (size_t)b * MAT;
    __shared__ float sv[N];
    __shared__ float part[32][65];
    int t = threadIdx.x;
    if (MODE == 0) {
        unsigned h = (unsigned)t * 1103515245u + 12345u;
        sv[t] = (float)((h >> 16) & 0x7fff) / 16384.f - 1.f;
    } else {
        sv[t] = vin[(size_t)b * N + t];
    }
    __syncthreads();

    int lane = t & 63, e = t >> 6;
    int j4 = (lane & 15) * 4;      // column offset within the 64-col group (quad)
    int cq = lane >> 4;            // row offset within a 4-row microstep
    int jb = g * 64;
    float a0 = 0.f, a1 = 0.f, a2 = 0.f, a3 = 0.f;
    #pragma unroll
    for (int c = 0; c < 64; c += 4) {
        int row = e * 64 + c + cq;
        ushort4 q = *(const ushort4*)&C[(size_t)row * N + jb + j4];
        float s = sv[row];
        a0 = fmaf(h2f(q.x), s, a0);
        a1 = fmaf(h2f(q.y), s, a1);
        a2 = fmaf(h2f(q.z), s, a2);
        a3 = fmaf(h2f(q.w), s, a3);
    }
    int pr = e * 4 + cq;
    part[pr][j4 + 0] = a0;
    part[pr][j4 + 1] = a1;
    part[pr][j4 + 2] = a2;
    part[pr][j4 + 3] = a3;
    __syncthreads();
    if (t < 64) {
        float o = 0.f;
        #pragma unroll
        for (int q = 0; q < 32; ++q) o += part[q][t];
        dst[(size_t)b * N + jb + t] = o;
        if (MODE == 2) {
            float val = o * o;
            #pragma unroll
            for (int s = 32; s; s >>= 1) val += __shfl_xor(val, s, 64);
            if (t == 0) atomicAdd(&ssout[b], val);
        }
    }
}

// ---------------- final: v_hat = v * rsqrt(ss); w = y * v_hat ----------------
// w[u] = sum_c yT[c][u] * v_hat[c].  Grid (8, NB), float4 column walk, same
// lane decomposition as k_piter.
__global__ __launch_bounds__(512) void k_wfin(const float* __restrict__ YT, const float* __restrict__ vin,
                                              const float* __restrict__ ss, float* __restrict__ vout,
                                              float* __restrict__ wout) {
    int b = blockIdx.y, g = blockIdx.x;
    const float* Yt = YT + (size_t)b * MAT;
    float rs = rsqrtf(ss[b]);
    __shared__ float sv[N];
    __shared__ float part[32][65];
    int t = threadIdx.x;
    sv[t] = vin[(size_t)b * N + t];        // unnormalized final iterate
    __syncthreads();

    int lane = t & 63, e = t >> 6;
    int j4 = (lane & 15) * 4;
    int cq = lane >> 4;
    int jb = g * 64;
    float a0 = 0.f, a1 = 0.f, a2 = 0.f, a3 = 0.f;
    #pragma unroll
    for (int c = 0; c < 64; c += 4) {
        int row = e * 64 + c + cq;
        float4 q = *(const float4*)&Yt[(size_t)row * N + jb + j4];
        float s = sv[row];
        a0 = fmaf(q.x, s, a0);
        a1 = fmaf(q.y, s, a1);
        a2 = fmaf(q.z, s, a2);
        a3 = fmaf(q.w, s, a3);
    }
    int pr = e * 4 + cq;
    part[pr][j4 + 0] = a0;
    part[pr][j4 + 1] = a1;
    part[pr][j4 + 2] = a2;
    part[pr][j4 + 3] = a3;
    __syncthreads();
    if (t < 64) {
        float w = 0.f;
        #pragma unroll
        for (int q = 0; q < 32; ++q) w += part[q][t];
        wout[(size_t)b * N + jb + t] = w * rs;
        vout[(size_t)b * N + jb + t] = sv[jb + t] * rs;
    }
}

// ---------------- out[b,i,j] = w[b,i] * v[b,j] ----------------
__global__ __launch_bounds__(256) void k_outer(const float* __restrict__ v, const float* __restrict__ w,
                                               float* __restrict__ out) {
    int tid = blockIdx.x * 256 + threadIdx.x;
    int b = tid >> 16;
    int rem = tid & 65535;
    int i = rem >> 7;
    int j4 = rem & 127;
    float wi = w[(size_t)b * N + i];
    float4 vv = ((const float4*)(v + (size_t)b * N))[j4];
    float4 o = {wi * vv.x, wi * vv.y, wi * vv.z, wi * vv.w};
    ((float4*)out)[tid] = o;
}

extern "C" void kernel_launch(void* const* d_in, const int* in_sizes, int n_in,
                              void* d_out, int out_size, void* d_ws, size_t ws_size,
                              hipStream_t stream) {
    const float* x = (const float*)d_in[0];
    float* out = (float*)d_out;
    char* base = (char*)d_ws;

    const size_t PL = (size_t)NB * MAT * sizeof(ushort);   // 16 MB per plane array
    ushort* AH = (ushort*)(base);
    ushort* AM = (ushort*)(base + PL);
    ushort* BH = (ushort*)(base + 2 * PL);
    ushort* BM = (ushort*)(base + 3 * PL);
    float*  fs = (float*)(base + 4 * PL);
    float*  vv = fs + 512;
    float*  ww = vv + (size_t)NB * N;
    float*  v2 = ww + (size_t)NB * N;
    float*  yT = out;                            // stage yT fp32 in d_out (read before k_outer overwrites)
    float*  ssf = fs + 256;                      // final ||v||^2 per batch (zeroed by memset below)

    hipMemsetAsync(fs, 0, 512 * sizeof(float), stream);
    k_luma<<<dim3(64, NB), 256, 0, stream>>>(x, yT, AH, AM);

    dim3 gg(512, 1, 1);   // 1D grid; in-kernel batch-clustered XCD decode
    // P1..P3 dual-plane (sensitive small-gap stages), P3 emits h-only; P4..P9 single-plane.
    k_gemm<2><<<gg, 256, 0, stream>>>(AH, AM, BH, BM,      nullptr,   fs + 0*32); // B      = yT yT^T
    k_gemm<2><<<gg, 256, 0, stream>>>(BH, BM, AH, AM,      fs + 0*32, fs + 1*32); // B^2
    k_gemm<2><<<gg, 256, 0, stream>>>(AH, AM, BH, nullptr, fs + 1*32, fs + 2*32); // B^4   (h only)
    k_gemm<1><<<gg, 256, 0, stream>>>(BH, nullptr, AH, nullptr, fs + 2*32, fs + 3*32); // B^8
    k_gemm<1><<<gg, 256, 0, stream>>>(AH, nullptr, BH, nullptr, fs + 3*32, fs + 4*32); // B^16
    k_gemm<1><<<gg, 256, 0, stream>>>(BH, nullptr, AH, nullptr, fs + 4*32, fs + 5*32); // B^32
    k_gemm<1><<<gg, 256, 0, stream>>>(AH, nullptr, BH, nullptr, fs + 5*32, fs + 6*32); // B^64
    k_gemm<1><<<gg, 256, 0, stream>>>(BH, nullptr, AH, nullptr, fs + 6*32, fs + 7*32); // B^128
    k_gemm<1><<<gg, 256, 0, stream>>>(AH, nullptr, BH, nullptr, fs + 7*32, nullptr);   // B^256 (h) -> BH

    // 8 distributed power-iteration matvecs on C = B^256 (256 blocks each),
    // unnormalized; final norm^2 accumulated by the last one.
    dim3 gp(8, NB);
    k_piter<0><<<gp, 512, 0, stream>>>(BH, nullptr, vv, nullptr);   // hash -> vv
    k_piter<1><<<gp, 512, 0, stream>>>(BH, vv, v2, nullptr);
    k_piter<1><<<gp, 512, 0, stream>>>(BH, v2, vv, nullptr);
    k_piter<1><<<gp, 512, 0, stream>>>(BH, vv, v2, nullptr);
    k_piter<1><<<gp, 512, 0, stream>>>(BH, v2, vv, nullptr);
    k_piter<1><<<gp, 512, 0, stream>>>(BH, vv, v2, nullptr);
    k_piter<1><<<gp, 512, 0, stream>>>(BH, v2, vv, nullptr);
    k_piter<2><<<gp, 512, 0, stream>>>(BH, vv, v2, ssf);            // + ||v||^2 -> ssf

    k_wfin<<<gp, 512, 0, stream>>>(yT, v2, ssf, vv, ww);            // v_hat -> vv, w -> ww
    k_outer<<<8192, 256, 0, stream>>>(vv, ww, out);
}

// Round 7
// 395.142 us; speedup vs baseline: 1.4298x; 1.0295x over previous
//
#include <hip/hip_runtime.h>
#include <hip/hip_fp16.h>

#define NB 32
#define N 512
#define MAT (N*N)   // 262144

typedef _Float16 half8 __attribute__((ext_vector_type(8)));
typedef float f32x4 __attribute__((ext_vector_type(4)));

#define MSCALE 2048.0f
#define RMSCALE (1.0f/2048.0f)

// split x into fp16 h + fp16 m' where x ~= h + m' * 2^-11 (m' scaled to avoid denormals)
__device__ inline ushort2 split2(float x) {
    __half h = __float2half(x);
    __half m = __float2half((x - __half2float(h)) * MSCALE);
    return make_ushort2(__half_as_ushort(h), __half_as_ushort(m));
}

// async global->LDS DMA, 16B per lane; LDS dest = wave-uniform base + lane*16
__device__ inline void gload(const ushort* g, ushort* l) {
    __builtin_amdgcn_global_load_lds((const __attribute__((address_space(1))) void*)g,
                                     (__attribute__((address_space(3))) void*)l, 16, 0, 0);
}

__device__ inline float h2f(ushort u) {
    return __half2float(__builtin_bit_cast(__half, u));
}

// counted vmcnt wait (wave-uniform n; immediates only)
__device__ inline void wvm(int n) {
    if (n == 0)      asm volatile("s_waitcnt vmcnt(0)" ::: "memory");
    else if (n == 2) asm volatile("s_waitcnt vmcnt(2)" ::: "memory");
    else             asm volatile("s_waitcnt vmcnt(4)" ::: "memory");
}

// ---------------- luma + transpose: yT fp32 + yT fp16 planes ----------------
__global__ __launch_bounds__(256) void k_luma(const float* __restrict__ x, float* __restrict__ yT,
                                              ushort* __restrict__ Ph, ushort* __restrict__ Pm) {
    int b = blockIdx.y;
    int tile = blockIdx.x;
    int TR = (tile >> 3) * 64;
    int TC = (tile & 7) * 64;
    __shared__ float ld[64][65];
    int t = threadIdx.x;
    int r0 = t >> 4;
    int c4 = (t & 15) * 4;
    const float* xb = x + (size_t)b * 3 * MAT;
    #pragma unroll
    for (int q = 0; q < 4; ++q) {
        int row = r0 + q * 16;
        size_t off = (size_t)(TR + row) * N + TC + c4;
        float4 rr = *(const float4*)&xb[off];
        float4 gg = *(const float4*)&xb[off + MAT];
        float4 bb = *(const float4*)&xb[off + 2 * MAT];
        ld[row][c4 + 0] = 0.299f * rr.x + 0.587f * gg.x + 0.114f * bb.x;
        ld[row][c4 + 1] = 0.299f * rr.y + 0.587f * gg.y + 0.114f * bb.y;
        ld[row][c4 + 2] = 0.299f * rr.z + 0.587f * gg.z + 0.114f * bb.z;
        ld[row][c4 + 3] = 0.299f * rr.w + 0.587f * gg.w + 0.114f * bb.w;
    }
    __syncthreads();
    float* yTb = yT + (size_t)b * MAT;
    ushort* PhB = Ph + (size_t)b * MAT;
    ushort* PmB = Pm + (size_t)b * MAT;
    #pragma unroll
    for (int q = 0; q < 4; ++q) {
        int i = r0 + q * 16;
        float v0 = ld[c4 + 0][i];
        float v1 = ld[c4 + 1][i];
        float v2 = ld[c4 + 2][i];
        float v3 = ld[c4 + 3][i];
        size_t off = (size_t)(TC + i) * N + TR + c4;
        *(float4*)&yTb[off] = make_float4(v0, v1, v2, v3);
        ushort2 s0 = split2(v0), s1 = split2(v1), s2 = split2(v2), s3 = split2(v3);
        *(ushort4*)&PhB[off] = make_ushort4(s0.x, s1.x, s2.x, s3.x);
        *(ushort4*)&PmB[off] = make_ushort4(s0.y, s1.y, s2.y, s3.y);
    }
}

// ---------------- MFMA GEMM: C = alpha * P * P^T from fp16 planes ----------------
// 1D grid, batch-clustered XCD decode (round 6). NPIN=1: 3-buffer ring, counted
// vmcnt(L), one raw s_barrier per K-step -> 2 tiles of prefetch in flight (MLP x2).
// NPIN=2: 2-buffer drain schedule (3-buf would be 96KB LDS -> 1 block/CU).
template<int NPIN>
__global__ __launch_bounds__(256, 2) void k_gemm(const ushort* __restrict__ Ph, const ushort* __restrict__ Pm,
                                                 ushort* __restrict__ Qh, ushort* __restrict__ Qm,
                                                 const float* __restrict__ fsrc, float* __restrict__ fdst) {
    constexpr int DEPTH = (NPIN == 1) ? 3 : 2;
    int bid = blockIdx.x;
    int xcd = bid & 7, q0 = bid >> 3;
    int b = xcd + 8 * (q0 >> 4);          // batch: 4 per XCD
    int tile = q0 & 15;                    // 16 tiles of this batch on the same XCD
    const ushort* PhB = Ph + (size_t)b * MAT;
    const ushort* PmB = (NPIN == 2) ? Pm + (size_t)b * MAT : nullptr;

    __shared__ __align__(16) ushort sI[DEPTH][NPIN][128 * 32];
    __shared__ __align__(16) ushort sJ[DEPTH][NPIN][128 * 32];

    int t = threadIdx.x;
    int iBase = (tile >> 2) * 128, jBase = (tile & 3) * 128;
    bool diag = (iBase == jBase);

    int lane = t & 63, wv = t >> 6;
    int wi = wv >> 1, wj = wv & 1;
    int cc = lane & 15, cq = lane >> 4;
    int q8 = cq * 8;
    int lrow = lane >> 2;
    int lseg = lane & 3;

    float alpha = fsrc ? (1.0f / fsrc[b]) : 1.0f;

    // stage one 32-wide K-tile into ring buffer `buf`
    auto stage = [&](int buf, int k0) {
        if (NPIN == 2) {
            if (diag) {
                #pragma unroll
                for (int j = 0; j < 4; ++j) {
                    int q = wv * 4 + j;
                    int pl = q >> 3, rg = q & 7;
                    const ushort* src = (pl ? PmB : PhB) + (size_t)(iBase + rg * 16 + lrow) * N + k0 + lseg * 8;
                    gload(src, &sI[buf][pl][rg * 512]);
                }
            } else {
                #pragma unroll
                for (int j = 0; j < 8; ++j) {
                    int q = wv * 8 + j;
                    int panel = q >> 4, pl = (q >> 3) & 1, rg = q & 7;
                    int rb = panel ? jBase : iBase;
                    const ushort* src = (pl ? PmB : PhB) + (size_t)(rb + rg * 16 + lrow) * N + k0 + lseg * 8;
                    gload(src, panel ? &sJ[buf][pl][rg * 512] : &sI[buf][pl][rg * 512]);
                }
            }
        } else {
            if (diag) {
                #pragma unroll
                for (int j = 0; j < 2; ++j) {
                    int rg = wv * 2 + j;
                    const ushort* src = PhB + (size_t)(iBase + rg * 16 + lrow) * N + k0 + lseg * 8;
                    gload(src, &sI[buf][0][rg * 512]);
                }
            } else {
                #pragma unroll
                for (int j = 0; j < 4; ++j) {
                    int q = wv * 4 + j;
                    int panel = q >> 3, rg = q & 7;
                    int rb = panel ? jBase : iBase;
                    const ushort* src = PhB + (size_t)(rb + rg * 16 + lrow) * N + k0 + lseg * 8;
                    gload(src, panel ? &sJ[buf][0][rg * 512] : &sI[buf][0][rg * 512]);
                }
            }
        }
    };

    f32x4 acc0[4][4], acc1[4][4];
    #pragma unroll
    for (int i = 0; i < 4; ++i)
        #pragma unroll
        for (int j = 0; j < 4; ++j) { acc0[i][j] = (f32x4)0.f; acc1[i][j] = (f32x4)0.f; }

    // MFMA on one staged K-tile
    auto mac = [&](int buf) {
        const ushort(*Ib)[128 * 32] = sI[buf];
        const ushort(*Jb)[128 * 32] = diag ? sI[buf] : sJ[buf];
        half8 bh[4], bm[4];
        #pragma unroll
        for (int ct = 0; ct < 4; ++ct) {
            int row = wj * 64 + ct * 16 + cc;
            bh[ct] = *(const half8*)&Jb[0][row * 32 + q8];
            if (NPIN == 2) bm[ct] = *(const half8*)&Jb[1][row * 32 + q8];
        }
        #pragma unroll
        for (int rt = 0; rt < 4; ++rt) {
            int row = wi * 64 + rt * 16 + cc;
            half8 ah = *(const half8*)&Ib[0][row * 32 + q8];
            half8 am;
            if (NPIN == 2) am = *(const half8*)&Ib[1][row * 32 + q8];
            #pragma unroll
            for (int ct = 0; ct < 4; ++ct) {
                acc0[rt][ct] = __builtin_amdgcn_mfma_f32_16x16x32_f16(ah, bh[ct], acc0[rt][ct], 0, 0, 0);
                if (NPIN == 2) {
                    acc1[rt][ct] = __builtin_amdgcn_mfma_f32_16x16x32_f16(ah, bm[ct], acc1[rt][ct], 0, 0, 0);
                    acc1[rt][ct] = __builtin_amdgcn_mfma_f32_16x16x32_f16(am, bh[ct], acc1[rt][ct], 0, 0, 0);
                }
            }
        }
    };

    if constexpr (DEPTH == 3) {
        // counted-vmcnt ring: tiles t+1, t+2 in flight while t computes.
        const int L = diag ? 2 : 4;                // gload wave-instrs per stage
        stage(0, 0);
        stage(1, 32);
        wvm(L);                                    // oldest L (tile 0) landed (own)
        __builtin_amdgcn_s_barrier();              // all waves' tile 0 landed
        for (int kt = 0; kt < 16; ++kt) {
            if (kt + 2 < 16) stage((kt + 2) % 3, (kt + 2) * 32);  // overwrites buf (kt-1)%3: reads done+barrier'd
            mac(kt % 3);
            if (kt + 2 < 16) wvm(L);               // own tile kt+1 landed (2L -> L outstanding)
            else if (kt + 1 < 16) wvm(0);          // tail: drain last tile
            if (kt + 1 < 16) __builtin_amdgcn_s_barrier();  // all waves: kt+1 landed, buf kt reads done
        }
    } else {
        // 2-buffer drain schedule (round 6)
        stage(0, 0);
        __syncthreads();
        for (int k0 = 0; k0 < N; k0 += 32) {
            int cur = (k0 >> 5) & 1;
            if (k0 + 32 < N) stage(cur ^ 1, k0 + 32);
            mac(cur);
            __syncthreads();
        }
    }

    ushort* QhB = Qh + (size_t)b * MAT;
    ushort* QmB = Qm ? Qm + (size_t)b * MAT : nullptr;
    float ss = 0.f;
    #pragma unroll
    for (int rt = 0; rt < 4; ++rt) {
        int i0 = iBase + wi * 64 + rt * 16 + cq * 4;
        #pragma unroll
        for (int ct = 0; ct < 4; ++ct) {
            int j0 = jBase + wj * 64 + ct * 16 + cc;
            #pragma unroll
            for (int r = 0; r < 4; ++r) {
                float o = acc0[rt][ct][r];
                if (NPIN == 2) o += acc1[rt][ct][r] * RMSCALE;
                o *= alpha;
                ss += o * o;
                size_t idx = (size_t)(i0 + r) * N + j0;
                if (QmB) {
                    ushort2 hm = split2(o);
                    QhB[idx] = hm.x;
                    QmB[idx] = hm.y;
                } else {
                    QhB[idx] = __half_as_ushort(__float2half(o));
                }
            }
        }
    }

    if (fdst) {
        for (int o = 32; o; o >>= 1) ss += __shfl_down(ss, o, 64);
        __shared__ float red[4];
        if (lane == 0) red[wv] = ss;
        __syncthreads();
        if (t == 0) atomicAdd(&fdst[b], red[0] + red[1] + red[2] + red[3]);
    }
}

// ---------------- distributed power iteration: one launch per matvec ----------------
// dst[b][j] = sum_c C[b][c][j] * src[b][c]   (C symmetric; column walk = coalesced).
// Grid (8, NB): 8 column-groups x 32 batches = 256 blocks, 512 threads.
// No per-iteration normalization: the GEMM chain's alpha scaling pins lambda1 ~ 1,
// so 8 unnormalized fp32 matvecs stay O(1); final norm applied in k_wfin.
// MODE 0: src = hash init (in-kernel). MODE 1: src = vin. MODE 2: src = vin and
// atomically accumulate ||dst||^2 into ssout[b].
template<int MODE>
__global__ __launch_bounds__(512) void k_piter(const ushort* __restrict__ Ch, const float* __restrict__ vin,
                                               float* __restrict__ dst, float* __restrict__ ssout) {
    int b = blockIdx.y, g = blockIdx.x;
    const ushort* C = Ch + (size_t)b * MAT;
    __shared__ float sv[N];
    __shared__ float part[32][65];
    int t = threadIdx.x;
    if (MODE == 0) {
        unsigned h = (unsigned)t * 1103515245u + 12345u;
        sv[t] = (float)((h >> 16) & 0x7fff) / 16384.f - 1.f;
    } else {
        sv[t] = vin[(size_t)b * N + t];
    }
    __syncthreads();

    int lane = t & 63, e = t >> 6;
    int j4 = (lane & 15) * 4;      // column offset within the 64-col group (quad)
    int cq = lane >> 4;            // row offset within a 4-row microstep
    int jb = g * 64;
    float a0 = 0.f, a1 = 0.f, a2 = 0.f, a3 = 0.f;
    #pragma unroll
    for (int c = 0; c < 64; c += 4) {
        int row = e * 64 + c + cq;
        ushort4 q = *(const ushort4*)&C[(size_t)row * N + jb + j4];
        float s = sv[row];
        a0 = fmaf(h2f(q.x), s, a0);
        a1 = fmaf(h2f(q.y), s, a1);
        a2 = fmaf(h2f(q.z), s, a2);
        a3 = fmaf(h2f(q.w), s, a3);
    }
    int pr = e * 4 + cq;
    part[pr][j4 + 0] = a0;
    part[pr][j4 + 1] = a1;
    part[pr][j4 + 2] = a2;
    part[pr][j4 + 3] = a3;
    __syncthreads();
    if (t < 64) {
        float o = 0.f;
        #pragma unroll
        for (int q = 0; q < 32; ++q) o += part[q][t];
        dst[(size_t)b * N + jb + t] = o;
        if (MODE == 2) {
            float val = o * o;
            #pragma unroll
            for (int s = 32; s; s >>= 1) val += __shfl_xor(val, s, 64);
            if (t == 0) atomicAdd(&ssout[b], val);
        }
    }
}

// ---------------- final: v_hat = v * rsqrt(ss); w = y * v_hat ----------------
// w[u] = sum_c yT[c][u] * v_hat[c].  Grid (8, NB), float4 column walk, same
// lane decomposition as k_piter.
__global__ __launch_bounds__(512) void k_wfin(const float* __restrict__ YT, const float* __restrict__ vin,
                                              const float* __restrict__ ss, float* __restrict__ vout,
                                              float* __restrict__ wout) {
    int b = blockIdx.y, g = blockIdx.x;
    const float* Yt = YT + (size_t)b * MAT;
    float rs = rsqrtf(ss[b]);
    __shared__ float sv[N];
    __shared__ float part[32][65];
    int t = threadIdx.x;
    sv[t] = vin[(size_t)b * N + t];        // unnormalized final iterate
    __syncthreads();

    int lane = t & 63, e = t >> 6;
    int j4 = (lane & 15) * 4;
    int cq = lane >> 4;
    int jb = g * 64;
    float a0 = 0.f, a1 = 0.f, a2 = 0.f, a3 = 0.f;
    #pragma unroll
    for (int c = 0; c < 64; c += 4) {
        int row = e * 64 + c + cq;
        float4 q = *(const float4*)&Yt[(size_t)row * N + jb + j4];
        float s = sv[row];
        a0 = fmaf(q.x, s, a0);
        a1 = fmaf(q.y, s, a1);
        a2 = fmaf(q.z, s, a2);
        a3 = fmaf(q.w, s, a3);
    }
    int pr = e * 4 + cq;
    part[pr][j4 + 0] = a0;
    part[pr][j4 + 1] = a1;
    part[pr][j4 + 2] = a2;
    part[pr][j4 + 3] = a3;
    __syncthreads();
    if (t < 64) {
        float w = 0.f;
        #pragma unroll
        for (int q = 0; q < 32; ++q) w += part[q][t];
        wout[(size_t)b * N + jb + t] = w * rs;
        vout[(size_t)b * N + jb + t] = sv[jb + t] * rs;
    }
}

// ---------------- out[b,i,j] = w[b,i] * v[b,j] ----------------
__global__ __launch_bounds__(256) void k_outer(const float* __restrict__ v, const float* __restrict__ w,
                                               float* __restrict__ out) {
    int tid = blockIdx.x * 256 + threadIdx.x;
    int b = tid >> 16;
    int rem = tid & 65535;
    int i = rem >> 7;
    int j4 = rem & 127;
    float wi = w[(size_t)b * N + i];
    float4 vv = ((const float4*)(v + (size_t)b * N))[j4];
    float4 o = {wi * vv.x, wi * vv.y, wi * vv.z, wi * vv.w};
    ((float4*)out)[tid] = o;
}

extern "C" void kernel_launch(void* const* d_in, const int* in_sizes, int n_in,
                              void* d_out, int out_size, void* d_ws, size_t ws_size,
                              hipStream_t stream) {
    const float* x = (const float*)d_in[0];
    float* out = (float*)d_out;
    char* base = (char*)d_ws;

    const size_t PL = (size_t)NB * MAT * sizeof(ushort);   // 16 MB per plane array
    ushort* AH = (ushort*)(base);
    ushort* AM = (ushort*)(base + PL);
    ushort* BH = (ushort*)(base + 2 * PL);
    ushort* BM = (ushort*)(base + 3 * PL);
    float*  fs = (float*)(base + 4 * PL);
    float*  vv = fs + 512;
    float*  ww = vv + (size_t)NB * N;
    float*  v2 = ww + (size_t)NB * N;
    float*  yT = out;                            // stage yT fp32 in d_out (read before k_outer overwrites)
    float*  ssf = fs + 256;                      // final ||v||^2 per batch (zeroed by memset below)

    hipMemsetAsync(fs, 0, 512 * sizeof(float), stream);
    k_luma<<<dim3(64, NB), 256, 0, stream>>>(x, yT, AH, AM);

    dim3 gg(512, 1, 1);   // 1D grid; in-kernel batch-clustered XCD decode
    // P1..P3 dual-plane (sensitive small-gap stages), P3 emits h-only; P4..P9 single-plane.
    k_gemm<2><<<gg, 256, 0, stream>>>(AH, AM, BH, BM,      nullptr,   fs + 0*32); // B      = yT yT^T
    k_gemm<2><<<gg, 256, 0, stream>>>(BH, BM, AH, AM,      fs + 0*32, fs + 1*32); // B^2
    k_gemm<2><<<gg, 256, 0, stream>>>(AH, AM, BH, nullptr, fs + 1*32, fs + 2*32); // B^4   (h only)
    k_gemm<1><<<gg, 256, 0, stream>>>(BH, nullptr, AH, nullptr, fs + 2*32, fs + 3*32); // B^8
    k_gemm<1><<<gg, 256, 0, stream>>>(AH, nullptr, BH, nullptr, fs + 3*32, fs + 4*32); // B^16
    k_gemm<1><<<gg, 256, 0, stream>>>(BH, nullptr, AH, nullptr, fs + 4*32, fs + 5*32); // B^32
    k_gemm<1><<<gg, 256, 0, stream>>>(AH, nullptr, BH, nullptr, fs + 5*32, fs + 6*32); // B^64
    k_gemm<1><<<gg, 256, 0, stream>>>(BH, nullptr, AH, nullptr, fs + 6*32, fs + 7*32); // B^128
    k_gemm<1><<<gg, 256, 0, stream>>>(AH, nullptr, BH, nullptr, fs + 7*32, nullptr);   // B^256 (h) -> BH

    // 8 distributed power-iteration matvecs on C = B^256 (256 blocks each),
    // unnormalized; final norm^2 accumulated by the last one.
    dim3 gp(8, NB);
    k_piter<0><<<gp, 512, 0, stream>>>(BH, nullptr, vv, nullptr);   // hash -> vv
    k_piter<1><<<gp, 512, 0, stream>>>(BH, vv, v2, nullptr);
    k_piter<1><<<gp, 512, 0, stream>>>(BH, v2, vv, nullptr);
    k_piter<1><<<gp, 512, 0, stream>>>(BH, vv, v2, nullptr);
    k_piter<1><<<gp, 512, 0, stream>>>(BH, v2, vv, nullptr);
    k_piter<1><<<gp, 512, 0, stream>>>(BH, vv, v2, nullptr);
    k_piter<1><<<gp, 512, 0, stream>>>(BH, v2, vv, nullptr);
    k_piter<2><<<gp, 512, 0, stream>>>(BH, vv, v2, ssf);            // + ||v||^2 -> ssf

    k_wfin<<<gp, 512, 0, stream>>>(yT, v2, ssf, vv, ww);            // v_hat -> vv, w -> ww
    k_outer<<<8192, 256, 0, stream>>>(vv, ww, out);
}